// Round 1
// baseline (10733.076 us; speedup 1.0000x reference)
//
#include <hip/hip_runtime.h>
#include <hip/hip_cooperative_groups.h>

namespace cg = cooperative_groups;

#define BB 64
#define TT 100
#define KSEL 2048
#define EMBD 300
#define EMBP 304
#define HH 512
#define GG 2048   // 4*H
#define NSYN 16

// ---------------- embedding gather (padded to 304 cols with zeros) ----------------
__global__ void embed_kernel(const int* __restrict__ X, const float* __restrict__ emb,
                             float* __restrict__ xemb) {
    int idx = blockIdx.x * blockDim.x + threadIdx.x;
    int total = BB * TT * EMBP;
    if (idx >= total) return;
    int row = idx / EMBP;
    int col = idx - row * EMBP;
    float v = 0.f;
    if (col < EMBD) v = emb[(size_t)X[row] * EMBD + col];
    xemb[idx] = v;
}

// ---------------- input projection GEMM ----------------
// C[m][n'] = sum_k A[m,k] * W[perm(n'),k] + b_ih[perm]+b_hh[perm]
// perm(n') = (n'&3)*512 + (n'>>2)  => gates for hdim j are contiguous float4 (i,f,g,o)
// AMODE 0: A row-major [6400][Kpad], m = b*100+t (xemb);  store gates[(t*64+b)*2048+n]
// AMODE 1: A = hseq0 layout [t][k][64b], m = t*64+b;      store gates[m*2048+n]
template<int AMODE>
__global__ void xproj_kernel(const float* __restrict__ A, const float* __restrict__ W,
                             const float* __restrict__ bih, const float* __restrict__ bhh,
                             float* __restrict__ gates, int Kreal, int Kpad) {
    __shared__ float As[16][68];
    __shared__ float Bs[16][68];
    int tid = threadIdx.x;
    int m0 = blockIdx.x * 64;
    int n0 = blockIdx.y * 64;
    int tx = tid & 15, ty = tid >> 4;
    float acc[4][4] = {};
    for (int k0 = 0; k0 < Kpad; k0 += 16) {
        if (AMODE == 0) {
            for (int e = tid; e < 1024; e += 256) {
                int ml = e >> 4, k = e & 15;
                As[k][ml] = A[(size_t)(m0 + ml) * Kpad + k0 + k];
            }
        } else {
            int t = m0 >> 6;
            for (int e = tid; e < 1024; e += 256) {
                int k = e >> 6, ml = e & 63;
                As[k][ml] = A[((size_t)t * 1024 + k0 + k) * 64 + ml];
            }
        }
        for (int e = tid; e < 1024; e += 256) {
            int nl = e >> 4, k = e & 15;
            int n = n0 + nl;
            int pr = (n & 3) * 512 + (n >> 2);
            int kk = k0 + k;
            Bs[k][nl] = (kk < Kreal) ? W[(size_t)pr * Kreal + kk] : 0.f;
        }
        __syncthreads();
#pragma unroll
        for (int kk = 0; kk < 16; kk++) {
            float4 a4 = *(const float4*)&As[kk][ty * 4];
            float4 b4 = *(const float4*)&Bs[kk][tx * 4];
            float av[4] = {a4.x, a4.y, a4.z, a4.w};
            float bv[4] = {b4.x, b4.y, b4.z, b4.w};
#pragma unroll
            for (int i = 0; i < 4; i++)
#pragma unroll
                for (int j = 0; j < 4; j++) acc[i][j] += av[i] * bv[j];
        }
        __syncthreads();
    }
    for (int i = 0; i < 4; i++) {
        int m = m0 + ty * 4 + i;
        size_t base;
        if (AMODE == 0) {
            int bidx = m / 100;
            int t = m - bidx * 100;
            base = ((size_t)(t * 64 + bidx)) * GG;
        } else {
            base = (size_t)m * GG;
        }
        for (int j = 0; j < 4; j++) {
            int n = n0 + tx * 4 + j;
            int pr = (n & 3) * 512 + (n >> 2);
            gates[base + n] = acc[i][j] + bih[pr] + bhh[pr];
        }
    }
}

// ---------------- recurrent bilstm layer (cooperative, both dirs) ----------------
// grid = 256 wgs x 256 threads. wgs 0..127: forward, 128..255: backward.
// wg owns 4 hdims j0..j0+3; thread = (b = tid&63, jl = tid>>6).
// W_hh rows staged transposed in LDS: wlds[k*16 + rl], row(rl) = (rl&3)*512 + j0 + (rl>>2)
// h shared through global double buffer hbuf[2][2dir][64][512]; one grid.sync per step.
__global__ void __launch_bounds__(256)
lstm_layer_kernel(const float* __restrict__ gates_f, const float* __restrict__ gates_b,
                  const float* __restrict__ whh_f, const float* __restrict__ whh_b,
                  const int* __restrict__ lengths,
                  float* __restrict__ hbuf,
                  float* __restrict__ hseq_out, int out_mode) {
    __shared__ float wlds[512 * 16];
    int bid = blockIdx.x;
    int dir = bid >> 7;
    int wg = bid & 127;
    int j0 = wg * 4;
    int tid = threadIdx.x;
    int b = tid & 63;
    int jl = tid >> 6;
    int j = j0 + jl;
    const float* Wrow = dir ? whh_b : whh_f;
    const float* gp_base = dir ? gates_b : gates_f;

    for (int idx = tid; idx < 16 * 512; idx += 256) {
        int rl = idx >> 9;
        int k = idx & 511;
        int row = (rl & 3) * 512 + (j0 + (rl >> 2));
        wlds[k * 16 + rl] = Wrow[(size_t)row * 512 + k];
    }
    // zero both h double-buffers (131072 floats total, 65536 threads)
    int gidx = bid * 256 + tid;
    hbuf[gidx] = 0.f;
    hbuf[gidx + 65536] = 0.f;
    float c = 0.f, h_own = 0.f;
    int len = lengths[b];
    cg::grid_group grid = cg::this_grid();
    __syncthreads();
    grid.sync();

    for (int s = 0; s < TT; s++) {
        int cur = s & 1;
        int t = dir ? (TT - 1 - s) : s;
        float4 g4 = *(const float4*)(gp_base + ((size_t)(t * 64 + b)) * GG + j * 4);
        float a0 = g4.x, a1 = g4.y, a2 = g4.z, a3 = g4.w;
        const float* hrow = hbuf + ((size_t)(cur * 2 + dir) * 64 + b) * 512;
#pragma unroll 4
        for (int k4 = 0; k4 < 128; k4++) {
            float4 h4 = *(const float4*)(hrow + k4 * 4);
            float hv[4] = {h4.x, h4.y, h4.z, h4.w};
#pragma unroll
            for (int kk = 0; kk < 4; kk++) {
                float4 w4 = *(const float4*)&wlds[(k4 * 4 + kk) * 16 + jl * 4];
                a0 += hv[kk] * w4.x;
                a1 += hv[kk] * w4.y;
                a2 += hv[kk] * w4.z;
                a3 += hv[kk] * w4.w;
            }
        }
        float i_s = 1.f / (1.f + __expf(-a0));
        float f_s = 1.f / (1.f + __expf(-a1));
        float g_t = tanhf(a2);
        float o_s = 1.f / (1.f + __expf(-a3));
        float c_new = f_s * c + i_s * g_t;
        float h_new = o_s * tanhf(c_new);
        if (t < len) { c = c_new; h_own = h_new; }
        hbuf[((size_t)((cur ^ 1) * 2 + dir) * 64 + b) * 512 + j] = h_own;
        if (out_mode == 0)
            hseq_out[((size_t)t * 1024 + dir * 512 + j) * 64 + b] = h_own;   // [t][k][b]
        else
            hseq_out[((size_t)b * TT + t) * 1024 + dir * 512 + j] = h_own;   // [b][t][k]
        grid.sync();
    }
}

// ---------------- ctx = xsel @ out_W^T + out_b ----------------
__global__ void ctx_kernel(const float* __restrict__ hseq1, const float* __restrict__ outW,
                           const float* __restrict__ outb, const int* __restrict__ sel_b,
                           const int* __restrict__ sel_t, float* __restrict__ out) {
    __shared__ float As[16][68];
    __shared__ float Bs[16][68];
    __shared__ int rowbase[64];
    int tid = threadIdx.x;
    int m0 = blockIdx.x * 64, n0 = blockIdx.y * 64;
    if (tid < 64) {
        int m = m0 + tid;
        rowbase[tid] = (sel_b[m] * TT + sel_t[m]) * 1024;
    }
    __syncthreads();
    int tx = tid & 15, ty = tid >> 4;
    float acc[4][4] = {};
    for (int k0 = 0; k0 < 1024; k0 += 16) {
        for (int e = tid; e < 1024; e += 256) {
            int ml = e >> 4, k = e & 15;
            As[k][ml] = hseq1[(size_t)rowbase[ml] + k0 + k];
        }
        for (int e = tid; e < 1024; e += 256) {
            int nl = e >> 4, k = e & 15;
            int n = n0 + nl;
            Bs[k][nl] = (n < EMBD) ? outW[(size_t)n * 1024 + k0 + k] : 0.f;
        }
        __syncthreads();
#pragma unroll
        for (int kk = 0; kk < 16; kk++) {
            float4 a4 = *(const float4*)&As[kk][ty * 4];
            float4 b4 = *(const float4*)&Bs[kk][tx * 4];
            float av[4] = {a4.x, a4.y, a4.z, a4.w};
            float bv[4] = {b4.x, b4.y, b4.z, b4.w};
#pragma unroll
            for (int i = 0; i < 4; i++)
#pragma unroll
                for (int j = 0; j < 4; j++) acc[i][j] += av[i] * bv[j];
        }
        __syncthreads();
    }
    for (int i = 0; i < 4; i++) {
        int m = m0 + ty * 4 + i;
        for (int j = 0; j < 4; j++) {
            int n = n0 + tx * 4 + j;
            if (n < EMBD) out[(size_t)m * EMBD + n] = acc[i][j] + outb[n];
        }
    }
}

// ---------------- cls = einsum('ksd,kd->ks', exp_W[eidx], xsel) + exp_b[eidx] ----------------
__global__ void cls_kernel(const float* __restrict__ hseq1, const float* __restrict__ expW,
                           const float* __restrict__ expb, const int* __restrict__ sel_b,
                           const int* __restrict__ sel_t, const int* __restrict__ eidx,
                           float* __restrict__ out) {
    __shared__ float xr[1024];
    int r = blockIdx.x;
    int tid = threadIdx.x;
    int e = eidx[r];
    int base = (sel_b[r] * TT + sel_t[r]) * 1024;
    for (int q = tid; q < 1024; q += 256) xr[q] = hseq1[(size_t)base + q];
    __syncthreads();
    int lane = tid & 63, wid = tid >> 6;
    for (int p = 0; p < 4; p++) {
        int s = p * 4 + wid;
        const float* wrow = expW + ((size_t)e * NSYN + s) * 1024;
        float partial = 0.f;
#pragma unroll
        for (int i = 0; i < 16; i++) {
            int k = lane + 64 * i;
            partial += xr[k] * wrow[k];
        }
        for (int off = 32; off; off >>= 1) partial += __shfl_down(partial, off);
        if (lane == 0) out[(size_t)KSEL * EMBD + (size_t)r * NSYN + s] = partial + expb[e * NSYN + s];
    }
}

extern "C" void kernel_launch(void* const* d_in, const int* in_sizes, int n_in,
                              void* d_out, int out_size, void* d_ws, size_t ws_size,
                              hipStream_t stream) {
    const int* X = (const int*)d_in[0];
    const int* Xlen = (const int*)d_in[1];
    const int* sel_b = (const int*)d_in[2];
    const int* sel_t = (const int*)d_in[3];
    const int* eidx = (const int*)d_in[4];
    const float* emb = (const float*)d_in[5];
    const float* w_ih_l0f = (const float*)d_in[6];
    const float* w_hh_l0f = (const float*)d_in[7];
    const float* b_ih_l0f = (const float*)d_in[8];
    const float* b_hh_l0f = (const float*)d_in[9];
    const float* w_ih_l0b = (const float*)d_in[10];
    const float* w_hh_l0b = (const float*)d_in[11];
    const float* b_ih_l0b = (const float*)d_in[12];
    const float* b_hh_l0b = (const float*)d_in[13];
    const float* w_ih_l1f = (const float*)d_in[14];
    const float* w_hh_l1f = (const float*)d_in[15];
    const float* b_ih_l1f = (const float*)d_in[16];
    const float* b_hh_l1f = (const float*)d_in[17];
    const float* w_ih_l1b = (const float*)d_in[18];
    const float* w_hh_l1b = (const float*)d_in[19];
    const float* b_ih_l1b = (const float*)d_in[20];
    const float* b_hh_l1b = (const float*)d_in[21];
    const float* outW = (const float*)d_in[22];
    const float* outb = (const float*)d_in[23];
    const float* expW = (const float*)d_in[24];
    const float* expb = (const float*)d_in[25];

    float* ws = (float*)d_ws;
    float* xemb   = ws;                                   // 6400*304      = 1,945,600
    float* gates_f = xemb + (size_t)6400 * EMBP;          // 100*64*2048   = 13,107,200
    float* gates_b = gates_f + (size_t)TT * BB * GG;
    float* hseq0  = gates_b + (size_t)TT * BB * GG;       // [t][1024][64] = 6,553,600
    float* hseq1  = hseq0 + (size_t)TT * 1024 * BB;       // [b][t][1024]  = 6,553,600
    float* hbuf   = hseq1 + (size_t)BB * TT * 1024;       // 2*2*64*512    = 131,072
    size_t needed = ((size_t)1945600 + 2 * 13107200 + 2 * 6553600 + 131072) * 4;
    if (ws_size < needed) return;  // diagnostic: absmax will equal max|ref| exactly
    float* out = (float*)d_out;

    int total = BB * TT * EMBP;
    embed_kernel<<<(total + 255) / 256, 256, 0, stream>>>(X, emb, xemb);

    dim3 gproj(100, 32);
    xproj_kernel<0><<<gproj, 256, 0, stream>>>(xemb, w_ih_l0f, b_ih_l0f, b_hh_l0f, gates_f, EMBD, EMBP);
    xproj_kernel<0><<<gproj, 256, 0, stream>>>(xemb, w_ih_l0b, b_ih_l0b, b_hh_l0b, gates_b, EMBD, EMBP);

    {
        int out_mode = 0;
        const float* gf = gates_f; const float* gb = gates_b;
        const float* wf = w_hh_l0f; const float* wb = w_hh_l0b;
        float* hb = hbuf; float* hs = hseq0;
        void* args[] = {(void*)&gf, (void*)&gb, (void*)&wf, (void*)&wb,
                        (void*)&Xlen, (void*)&hb, (void*)&hs, (void*)&out_mode};
        hipLaunchCooperativeKernel((const void*)lstm_layer_kernel, dim3(256), dim3(256), args, 0, stream);
    }

    xproj_kernel<1><<<gproj, 256, 0, stream>>>(hseq0, w_ih_l1f, b_ih_l1f, b_hh_l1f, gates_f, 1024, 1024);
    xproj_kernel<1><<<gproj, 256, 0, stream>>>(hseq0, w_ih_l1b, b_ih_l1b, b_hh_l1b, gates_b, 1024, 1024);

    {
        int out_mode = 1;
        const float* gf = gates_f; const float* gb = gates_b;
        const float* wf = w_hh_l1f; const float* wb = w_hh_l1b;
        float* hb = hbuf; float* hs = hseq1;
        void* args[] = {(void*)&gf, (void*)&gb, (void*)&wf, (void*)&wb,
                        (void*)&Xlen, (void*)&hb, (void*)&hs, (void*)&out_mode};
        hipLaunchCooperativeKernel((const void*)lstm_layer_kernel, dim3(256), dim3(256), args, 0, stream);
    }

    ctx_kernel<<<dim3(32, 5), 256, 0, stream>>>(hseq1, outW, outb, sel_b, sel_t, out);
    cls_kernel<<<KSEL, 256, 0, stream>>>(hseq1, expW, expb, sel_b, sel_t, eidx, out);
}